// Round 4
// baseline (154.975 us; speedup 1.0000x reference)
//
#include <hip/hip_runtime.h>

#define D 128

typedef float f32x4 __attribute__((ext_vector_type(4)));

// ---------------------------------------------------------------------------
// Kernel 0: fold the two linear chains into fused affine maps, stored in ws:
//   ws[0..383]    : J_enc [3][128]  = We3@We2@We1
//   ws[384..386]  : b_enc [3]       = We3@(We2@be1 + be2) + be3
//   ws[512..1023] : J_dec4 [128][4] = (J_dec[c][0..2], b_dec[c])
//                   J_dec = Wd3@Wd2@Wd1, b_dec = Wd3@(Wd2@bd1 + bd2) + bd3
// ---------------------------------------------------------------------------
__global__ __launch_bounds__(256) void fuse_weights(
    const float* __restrict__ We1, const float* __restrict__ be1,
    const float* __restrict__ We2, const float* __restrict__ be2,
    const float* __restrict__ We3, const float* __restrict__ be3,
    const float* __restrict__ Wd1, const float* __restrict__ bd1,
    const float* __restrict__ Wd2, const float* __restrict__ bd2,
    const float* __restrict__ Wd3, const float* __restrict__ bd3,
    float* __restrict__ ws)
{
    __shared__ float A1[3][64];   // We3@We2
    __shared__ float B1[64][3];   // Wd2@Wd1
    __shared__ float t2d[64];     // Wd2@bd1 + bd2
    const int t = threadIdx.x;

    if (t < 192) {
        {   int r = t >> 6, c = t & 63;
            float s = 0.f;
            #pragma unroll 8
            for (int i = 0; i < 32; ++i) s += We3[r * 32 + i] * We2[i * 64 + c];
            A1[r][c] = s;
        }
        {   int o = t / 3, l = t - o * 3;
            float s = 0.f;
            #pragma unroll 8
            for (int i = 0; i < 32; ++i) s += Wd2[o * 32 + i] * Wd1[i * 3 + l];
            B1[o][l] = s;
        }
    } else {
        int i = t - 192;
        float s = bd2[i];
        #pragma unroll 8
        for (int j = 0; j < 32; ++j) s += Wd2[i * 32 + j] * bd1[j];
        t2d[i] = s;
    }
    __syncthreads();

    for (int e = t; e < 3 * D; e += 256) {
        int r = e >> 7, c = e & 127;
        float s = 0.f;
        #pragma unroll 8
        for (int j = 0; j < 64; ++j) s += A1[r][j] * We1[j * D + c];
        ws[e] = s;
    }
    if (t < 3) {
        float s = be3[t];
        #pragma unroll 8
        for (int j = 0; j < 64; ++j) s += A1[t][j] * be1[j];
        #pragma unroll 8
        for (int i = 0; i < 32; ++i) s += We3[t * 32 + i] * be2[i];
        ws[384 + t] = s;
    }
    if (t < 128) {
        float s0 = 0.f, s1 = 0.f, s2 = 0.f, sb = bd3[t];
        #pragma unroll 8
        for (int j = 0; j < 64; ++j) {
            float w = Wd3[t * 64 + j];
            s0 += w * B1[j][0];
            s1 += w * B1[j][1];
            s2 += w * B1[j][2];
            sb += w * t2d[j];
        }
        ws[512 + t * 4 + 0] = s0;
        ws[512 + t * 4 + 1] = s1;
        ws[512 + t * 4 + 2] = s2;
        ws[512 + t * 4 + 3] = sb;
    }
}

// ---------------------------------------------------------------------------
// Kernel 1: encoder + SINDy, ROW PER THREAD (no shuffles, no reduction).
// Each thread reads its own 128-float row of x and dx as 32 strided f32x4
// loads; consecutive f32x4s of a lane cover full 64B lines (MSHR-merged).
// J_enc / EW / biases staged in LDS, read at uniform addresses (broadcast).
// Writes z @ 0 [N,3], dz @ 3N, dzb @ 6N.
// ---------------------------------------------------------------------------
__global__ __launch_bounds__(256) void enc_rpt(
    const float* __restrict__ x, const float* __restrict__ dx,
    const float* __restrict__ EW, const float* __restrict__ Eb,
    const float* __restrict__ ws, float* __restrict__ out, int nrows)
{
    __shared__ float sje[384];   // J_enc rows 0,1,2 (128 each)
    __shared__ float sew[66];    // EW [3][22]
    __shared__ float sbe[6];     // b_enc[3], Eb[3]
    const int t = threadIdx.x;

    if (t < 128) { sje[t] = ws[t]; sje[128 + t] = ws[128 + t]; sje[256 + t] = ws[256 + t]; }
    else if (t < 194) sew[t - 128] = EW[t - 128];
    else if (t < 197) { sbe[t - 194] = ws[384 + (t - 194)]; sbe[3 + (t - 194)] = Eb[t - 194]; }
    __syncthreads();

    const int row = blockIdx.x * 256 + t;
    if (row >= nrows) return;

    const f32x4* xr  = (const f32x4*)(x  + (size_t)row * D);
    const f32x4* dxr = (const f32x4*)(dx + (size_t)row * D);

    float z0 = 0.f, z1 = 0.f, z2 = 0.f, d0 = 0.f, d1 = 0.f, d2 = 0.f;

    #pragma unroll 2
    for (int c = 0; c < 8; ++c) {
        const f32x4* j0 = (const f32x4*)(sje +   0 + c * 16);
        const f32x4* j1 = (const f32x4*)(sje + 128 + c * 16);
        const f32x4* j2 = (const f32x4*)(sje + 256 + c * 16);
        #pragma unroll
        for (int q = 0; q < 4; ++q) {
            const f32x4 xv = xr[c * 4 + q];
            const f32x4 dv = dxr[c * 4 + q];
            const f32x4 a = j0[q], b = j1[q], g = j2[q];
            z0 += a.x*xv.x + a.y*xv.y + a.z*xv.z + a.w*xv.w;
            z1 += b.x*xv.x + b.y*xv.y + b.z*xv.z + b.w*xv.w;
            z2 += g.x*xv.x + g.y*xv.y + g.z*xv.z + g.w*xv.w;
            d0 += a.x*dv.x + a.y*dv.y + a.z*dv.z + a.w*dv.w;
            d1 += b.x*dv.x + b.y*dv.y + b.z*dv.z + b.w*dv.w;
            d2 += g.x*dv.x + g.y*dv.y + g.z*dv.z + g.w*dv.w;
        }
    }

    z0 += sbe[0]; z1 += sbe[1]; z2 += sbe[2];

    // SINDy library (constant terms folded into bias)
    const float q00 = z0*z0, q01 = z0*z1, q02 = z0*z2;
    const float q11 = z1*z1, q12 = z1*z2, q22 = z2*z2;
    float th[19];
    th[0]=z0;  th[1]=z1;  th[2]=z2;
    th[3]=q00; th[4]=q01; th[5]=q02; th[6]=q11; th[7]=q12; th[8]=q22;
    th[9]=q00*z0;  th[10]=q00*z1; th[11]=q00*z2;
    th[12]=q11*z0; th[13]=q12*z0; th[14]=q22*z0;
    th[15]=q11*z1; th[16]=q11*z2; th[17]=q22*z1; th[18]=q22*z2;

    float b0 = sbe[3] + sew[0]  + sew[1]  + sew[2];
    float b1 = sbe[4] + sew[22] + sew[23] + sew[24];
    float b2 = sbe[5] + sew[44] + sew[45] + sew[46];
    #pragma unroll
    for (int k = 0; k < 19; ++k) {
        b0 += sew[3  + k] * th[k];
        b1 += sew[25 + k] * th[k];
        b2 += sew[47 + k] * th[k];
    }

    const size_t n3 = (size_t)row * 3;
    out[n3 + 0] = z0;  out[n3 + 1] = z1;  out[n3 + 2] = z2;
    float* o2 = out + 3 * (size_t)nrows;
    o2[n3 + 0] = d0;  o2[n3 + 1] = d1;  o2[n3 + 2] = d2;
    float* o3 = out + 6 * (size_t)nrows;
    o3[n3 + 0] = b0;  o3[n3 + 1] = b1;  o3[n3 + 2] = b2;
}

// ---------------------------------------------------------------------------
// Kernel 2: decoder. Reads z, dzb (tiny, L3-hot); writes xb, dxb coalesced.
// Half-wave per row; block owns 128 contiguous rows; unguarded fast path.
// ---------------------------------------------------------------------------
__global__ __launch_bounds__(256) void dec_kernel(
    const float* __restrict__ ws, const float* __restrict__ zin,
    const float* __restrict__ dzbin, float* __restrict__ xbout,
    float* __restrict__ dxbout, int nrows)
{
    const int lane = threadIdx.x & 31;
    const int half = threadIdx.x >> 5;

    const f32x4 jd0 = *((const f32x4*)(ws + 512) + lane * 4 + 0);
    const f32x4 jd1 = *((const f32x4*)(ws + 512) + lane * 4 + 1);
    const f32x4 jd2 = *((const f32x4*)(ws + 512) + lane * 4 + 2);
    const f32x4 jd3 = *((const f32x4*)(ws + 512) + lane * 4 + 3);

    const int base = blockIdx.x * 128;

#define DEC_BODY(ROW)                                                         \
    {                                                                         \
        const int row = (ROW);                                                \
        const float z0 = zin[row * 3 + 0];                                    \
        const float z1 = zin[row * 3 + 1];                                    \
        const float z2 = zin[row * 3 + 2];                                    \
        const float b0 = dzbin[row * 3 + 0];                                  \
        const float b1 = dzbin[row * 3 + 1];                                  \
        const float b2 = dzbin[row * 3 + 2];                                  \
        f32x4 xbv, dxbv;                                                      \
        xbv.x  = jd0.x*z0 + jd0.y*z1 + jd0.z*z2 + jd0.w;                      \
        xbv.y  = jd1.x*z0 + jd1.y*z1 + jd1.z*z2 + jd1.w;                      \
        xbv.z  = jd2.x*z0 + jd2.y*z1 + jd2.z*z2 + jd2.w;                      \
        xbv.w  = jd3.x*z0 + jd3.y*z1 + jd3.z*z2 + jd3.w;                      \
        dxbv.x = jd0.x*b0 + jd0.y*b1 + jd0.z*b2;                              \
        dxbv.y = jd1.x*b0 + jd1.y*b1 + jd1.z*b2;                              \
        dxbv.z = jd2.x*b0 + jd2.y*b1 + jd2.z*b2;                              \
        dxbv.w = jd3.x*b0 + jd3.y*b1 + jd3.z*b2;                              \
        *((f32x4*)(xbout  + (size_t)row * D) + lane) = xbv;                   \
        *((f32x4*)(dxbout + (size_t)row * D) + lane) = dxbv;                  \
    }

    if (base + 128 <= nrows) {
        #pragma unroll 4
        for (int i = 0; i < 16; ++i) DEC_BODY(base + i * 8 + half);
    } else {
        for (int i = 0; i < 16; ++i) {
            const int r = base + i * 8 + half;
            if (r < nrows) DEC_BODY(r);
        }
    }
#undef DEC_BODY
}

extern "C" void kernel_launch(void* const* d_in, const int* in_sizes, int n_in,
                              void* d_out, int out_size, void* d_ws, size_t ws_size,
                              hipStream_t stream) {
    const float* x   = (const float*)d_in[0];
    const float* dx  = (const float*)d_in[1];
    const float* We1 = (const float*)d_in[2];
    const float* be1 = (const float*)d_in[3];
    const float* We2 = (const float*)d_in[4];
    const float* be2 = (const float*)d_in[5];
    const float* We3 = (const float*)d_in[6];
    const float* be3 = (const float*)d_in[7];
    const float* Wd1 = (const float*)d_in[8];
    const float* bd1 = (const float*)d_in[9];
    const float* Wd2 = (const float*)d_in[10];
    const float* bd2 = (const float*)d_in[11];
    const float* Wd3 = (const float*)d_in[12];
    const float* bd3 = (const float*)d_in[13];
    const float* EW  = (const float*)d_in[14];
    const float* Eb  = (const float*)d_in[15];

    float* ws  = (float*)d_ws;
    float* out = (float*)d_out;
    const int nrows = in_sizes[0] / D;          // 262144
    const int nblk_enc = (nrows + 255) / 256;   // 1024
    const int nblk_dec = (nrows + 127) / 128;   // 2048

    fuse_weights<<<1, 256, 0, stream>>>(We1, be1, We2, be2, We3, be3,
                                        Wd1, bd1, Wd2, bd2, Wd3, bd3, ws);

    enc_rpt<<<nblk_enc, 256, 0, stream>>>(x, dx, EW, Eb, ws, out, nrows);

    dec_kernel<<<nblk_dec, 256, 0, stream>>>(ws,
                                             out,                       // z
                                             out + 6 * (size_t)nrows,   // dzb
                                             out + 9 * (size_t)nrows,   // xb
                                             out + 137 * (size_t)nrows, // dxb
                                             nrows);
}

// Round 5
// 121.277 us; speedup vs baseline: 1.2779x; 1.2779x over previous
//
#include <hip/hip_runtime.h>

#define D 128

typedef float f32x4 __attribute__((ext_vector_type(4)));

// ---------------------------------------------------------------------------
// Kernel 0: fold the two linear chains into fused affine maps, stored in ws:
//   ws[0..383]    : J_enc [3][128]  = We3@We2@We1
//   ws[384..386]  : b_enc [3]       = We3@(We2@be1 + be2) + be3
//   ws[512..1023] : J_dec4 [128][4] = (J_dec[c][0..2], b_dec[c])
//                   J_dec = Wd3@Wd2@Wd1, b_dec = Wd3@(Wd2@bd1 + bd2) + bd3
// ---------------------------------------------------------------------------
__global__ __launch_bounds__(256) void fuse_weights(
    const float* __restrict__ We1, const float* __restrict__ be1,
    const float* __restrict__ We2, const float* __restrict__ be2,
    const float* __restrict__ We3, const float* __restrict__ be3,
    const float* __restrict__ Wd1, const float* __restrict__ bd1,
    const float* __restrict__ Wd2, const float* __restrict__ bd2,
    const float* __restrict__ Wd3, const float* __restrict__ bd3,
    float* __restrict__ ws)
{
    __shared__ float A1[3][64];   // We3@We2
    __shared__ float B1[64][3];   // Wd2@Wd1
    __shared__ float t2d[64];     // Wd2@bd1 + bd2
    const int t = threadIdx.x;

    if (t < 192) {
        {   int r = t >> 6, c = t & 63;
            float s = 0.f;
            #pragma unroll 8
            for (int i = 0; i < 32; ++i) s += We3[r * 32 + i] * We2[i * 64 + c];
            A1[r][c] = s;
        }
        {   int o = t / 3, l = t - o * 3;
            float s = 0.f;
            #pragma unroll 8
            for (int i = 0; i < 32; ++i) s += Wd2[o * 32 + i] * Wd1[i * 3 + l];
            B1[o][l] = s;
        }
    } else {
        int i = t - 192;
        float s = bd2[i];
        #pragma unroll 8
        for (int j = 0; j < 32; ++j) s += Wd2[i * 32 + j] * bd1[j];
        t2d[i] = s;
    }
    __syncthreads();

    for (int e = t; e < 3 * D; e += 256) {
        int r = e >> 7, c = e & 127;
        float s = 0.f;
        #pragma unroll 8
        for (int j = 0; j < 64; ++j) s += A1[r][j] * We1[j * D + c];
        ws[e] = s;
    }
    if (t < 3) {
        float s = be3[t];
        #pragma unroll 8
        for (int j = 0; j < 64; ++j) s += A1[t][j] * be1[j];
        #pragma unroll 8
        for (int i = 0; i < 32; ++i) s += We3[t * 32 + i] * be2[i];
        ws[384 + t] = s;
    }
    if (t < 128) {
        float s0 = 0.f, s1 = 0.f, s2 = 0.f, sb = bd3[t];
        #pragma unroll 8
        for (int j = 0; j < 64; ++j) {
            float w = Wd3[t * 64 + j];
            s0 += w * B1[j][0];
            s1 += w * B1[j][1];
            s2 += w * B1[j][2];
            sb += w * t2d[j];
        }
        ws[512 + t * 4 + 0] = s0;
        ws[512 + t * 4 + 1] = s1;
        ws[512 + t * 4 + 2] = s2;
        ws[512 + t * 4 + 3] = sb;
    }
}

// ---------------------------------------------------------------------------
// Kernel 1: encoder only, LOW-REGISTER (no EW/theta). Half-wave per row,
// coalesced f32x4 nt-loads, 3-value butterfly per phase.
//   Phase 1: x  -> z  (single read stream)
//   Phase 2: dx -> dz (single read stream)
// ~40 VGPR -> 8 waves/SIMD for max loads in flight.
// ---------------------------------------------------------------------------
__global__ __launch_bounds__(256) void enc2(
    const float* __restrict__ x, const float* __restrict__ dx,
    const float* __restrict__ ws, float* __restrict__ zout,
    float* __restrict__ dzout, int nrows)
{
    const int lane = threadIdx.x & 31;
    const int half = threadIdx.x >> 5;

    const f32x4 je0 = *((const f32x4*)(ws + 0 * D) + lane);
    const f32x4 je1 = *((const f32x4*)(ws + 1 * D) + lane);
    const f32x4 je2 = *((const f32x4*)(ws + 2 * D) + lane);
    const float benc0 = ws[384], benc1 = ws[385], benc2 = ws[386];

    const int base = blockIdx.x * 128;

    // ---- Phase 1: x -> z ----
    #pragma unroll 4
    for (int i = 0; i < 16; ++i) {
        const int row = base + i * 8 + half;
        if (row >= nrows) continue;
        const f32x4 xv = __builtin_nontemporal_load((const f32x4*)(x + (size_t)row * D) + lane);
        float z0 = je0.x*xv.x + je0.y*xv.y + je0.z*xv.z + je0.w*xv.w;
        float z1 = je1.x*xv.x + je1.y*xv.y + je1.z*xv.z + je1.w*xv.w;
        float z2 = je2.x*xv.x + je2.y*xv.y + je2.z*xv.z + je2.w*xv.w;
        #pragma unroll
        for (int m = 16; m >= 1; m >>= 1) {
            z0 += __shfl_xor(z0, m);
            z1 += __shfl_xor(z1, m);
            z2 += __shfl_xor(z2, m);
        }
        if (lane < 3) {
            const float zv = (lane == 0) ? z0 + benc0 : (lane == 1) ? z1 + benc1 : z2 + benc2;
            zout[(size_t)row * 3 + lane] = zv;
        }
    }

    __syncthreads();   // keep block's waves phase-aligned (stream purity)

    // ---- Phase 2: dx -> dz ----
    #pragma unroll 4
    for (int i = 0; i < 16; ++i) {
        const int row = base + i * 8 + half;
        if (row >= nrows) continue;
        const f32x4 dv = __builtin_nontemporal_load((const f32x4*)(dx + (size_t)row * D) + lane);
        float d0 = je0.x*dv.x + je0.y*dv.y + je0.z*dv.z + je0.w*dv.w;
        float d1 = je1.x*dv.x + je1.y*dv.y + je1.z*dv.z + je1.w*dv.w;
        float d2 = je2.x*dv.x + je2.y*dv.y + je2.z*dv.z + je2.w*dv.w;
        #pragma unroll
        for (int m = 16; m >= 1; m >>= 1) {
            d0 += __shfl_xor(d0, m);
            d1 += __shfl_xor(d1, m);
            d2 += __shfl_xor(d2, m);
        }
        if (lane < 3) {
            const float dvv = (lane == 0) ? d0 : (lane == 1) ? d1 : d2;
            dzout[(size_t)row * 3 + lane] = dvv;
        }
    }
}

// ---------------------------------------------------------------------------
// Kernel 2: SINDy + decoder (register-heavy side; store-bound so occupancy
// is not critical). Half-wave per row.
//   Phase 1: read z (L3-hot), theta -> dzb (write + LDS stash), xb stream
//   Phase 2: LDS dzb -> dxb stream
// ---------------------------------------------------------------------------
__global__ __launch_bounds__(256) void dec2(
    const float* __restrict__ ws, const float* __restrict__ EW,
    const float* __restrict__ Eb, const float* __restrict__ zin,
    float* __restrict__ dzbout, float* __restrict__ xbout,
    float* __restrict__ dxbout, int nrows)
{
    __shared__ float sdzb[384];   // [128 rows][3]

    const int lane = threadIdx.x & 31;
    const int half = threadIdx.x >> 5;

    const f32x4 jd0 = *((const f32x4*)(ws + 512) + lane * 4 + 0);
    const f32x4 jd1 = *((const f32x4*)(ws + 512) + lane * 4 + 1);
    const f32x4 jd2 = *((const f32x4*)(ws + 512) + lane * 4 + 2);
    const f32x4 jd3 = *((const f32x4*)(ws + 512) + lane * 4 + 3);

    // EW rows (constant-term columns folded into bias)
    float ew0[19], ew1[19], ew2[19];
    #pragma unroll
    for (int k = 0; k < 19; ++k) {
        ew0[k] = EW[ 3 + k];
        ew1[k] = EW[25 + k];
        ew2[k] = EW[47 + k];
    }
    const float bs0 = Eb[0] + EW[ 0] + EW[ 1] + EW[ 2];
    const float bs1 = Eb[1] + EW[22] + EW[23] + EW[24];
    const float bs2 = Eb[2] + EW[44] + EW[45] + EW[46];

    const int base = blockIdx.x * 128;

    // ---- Phase 1: z -> dzb (small) + xb (big stream) ----
    #pragma unroll 2
    for (int i = 0; i < 16; ++i) {
        const int r2  = i * 8 + half;
        const int row = base + r2;
        if (row >= nrows) continue;

        const float z0 = zin[(size_t)row * 3 + 0];
        const float z1 = zin[(size_t)row * 3 + 1];
        const float z2 = zin[(size_t)row * 3 + 2];

        const float q00 = z0*z0, q01 = z0*z1, q02 = z0*z2;
        const float q11 = z1*z1, q12 = z1*z2, q22 = z2*z2;
        float th[19];
        th[0]=z0;  th[1]=z1;  th[2]=z2;
        th[3]=q00; th[4]=q01; th[5]=q02; th[6]=q11; th[7]=q12; th[8]=q22;
        th[9]=q00*z0;  th[10]=q00*z1; th[11]=q00*z2;
        th[12]=q11*z0; th[13]=q12*z0; th[14]=q22*z0;
        th[15]=q11*z1; th[16]=q11*z2; th[17]=q22*z1; th[18]=q22*z2;

        float b0 = bs0, b1 = bs1, b2 = bs2;
        #pragma unroll
        for (int k = 0; k < 19; ++k) {
            b0 += ew0[k] * th[k];
            b1 += ew1[k] * th[k];
            b2 += ew2[k] * th[k];
        }

        if (lane < 3) {
            const float bv = (lane == 0) ? b0 : (lane == 1) ? b1 : b2;
            dzbout[(size_t)row * 3 + lane] = bv;
            sdzb[r2 * 3 + lane] = bv;
        }

        f32x4 xbv;
        xbv.x = jd0.x*z0 + jd0.y*z1 + jd0.z*z2 + jd0.w;
        xbv.y = jd1.x*z0 + jd1.y*z1 + jd1.z*z2 + jd1.w;
        xbv.z = jd2.x*z0 + jd2.y*z1 + jd2.z*z2 + jd2.w;
        xbv.w = jd3.x*z0 + jd3.y*z1 + jd3.z*z2 + jd3.w;
        __builtin_nontemporal_store(xbv, (f32x4*)(xbout + (size_t)row * D) + lane);
    }

    __syncthreads();

    // ---- Phase 2: dxb (big stream) from LDS dzb ----
    #pragma unroll 4
    for (int i = 0; i < 16; ++i) {
        const int r2  = i * 8 + half;
        const int row = base + r2;
        if (row >= nrows) continue;

        const float b0 = sdzb[r2 * 3 + 0];
        const float b1 = sdzb[r2 * 3 + 1];
        const float b2 = sdzb[r2 * 3 + 2];

        f32x4 dxbv;
        dxbv.x = jd0.x*b0 + jd0.y*b1 + jd0.z*b2;
        dxbv.y = jd1.x*b0 + jd1.y*b1 + jd1.z*b2;
        dxbv.z = jd2.x*b0 + jd2.y*b1 + jd2.z*b2;
        dxbv.w = jd3.x*b0 + jd3.y*b1 + jd3.z*b2;
        __builtin_nontemporal_store(dxbv, (f32x4*)(dxbout + (size_t)row * D) + lane);
    }
}

extern "C" void kernel_launch(void* const* d_in, const int* in_sizes, int n_in,
                              void* d_out, int out_size, void* d_ws, size_t ws_size,
                              hipStream_t stream) {
    const float* x   = (const float*)d_in[0];
    const float* dx  = (const float*)d_in[1];
    const float* We1 = (const float*)d_in[2];
    const float* be1 = (const float*)d_in[3];
    const float* We2 = (const float*)d_in[4];
    const float* be2 = (const float*)d_in[5];
    const float* We3 = (const float*)d_in[6];
    const float* be3 = (const float*)d_in[7];
    const float* Wd1 = (const float*)d_in[8];
    const float* bd1 = (const float*)d_in[9];
    const float* Wd2 = (const float*)d_in[10];
    const float* bd2 = (const float*)d_in[11];
    const float* Wd3 = (const float*)d_in[12];
    const float* bd3 = (const float*)d_in[13];
    const float* EW  = (const float*)d_in[14];
    const float* Eb  = (const float*)d_in[15];

    float* ws  = (float*)d_ws;
    float* out = (float*)d_out;
    const int nrows = in_sizes[0] / D;        // 262144
    const int nblk  = (nrows + 127) / 128;    // 2048

    fuse_weights<<<1, 256, 0, stream>>>(We1, be1, We2, be2, We3, be3,
                                        Wd1, bd1, Wd2, bd2, Wd3, bd3, ws);

    enc2<<<nblk, 256, 0, stream>>>(x, dx, ws,
                                   out,                      // z
                                   out + 3 * (size_t)nrows,  // dz
                                   nrows);

    dec2<<<nblk, 256, 0, stream>>>(ws, EW, Eb,
                                   out,                       // z
                                   out + 6 * (size_t)nrows,   // dzb
                                   out + 9 * (size_t)nrows,   // xb
                                   out + 137 * (size_t)nrows, // dxb
                                   nrows);
}